// Round 1
// baseline (544.581 us; speedup 1.0000x reference)
//
#include <hip/hip_runtime.h>
#include <stdint.h>

#define MB (1u << 20)

typedef __attribute__((ext_vector_type(8))) short bf16x8;
typedef __attribute__((ext_vector_type(4))) float f32x4;

__device__ __forceinline__ float b2f(unsigned short u) {
  union { unsigned int i; float f; } c; c.i = ((unsigned int)u) << 16; return c.f;
}
__device__ __forceinline__ unsigned short f2b(float f) {
  union { float f; unsigned int i; } c; c.f = f;
  unsigned int r = c.i + 0x7fffu + ((c.i >> 16) & 1u);
  return (unsigned short)(r >> 16);
}

// ---------------- f32 -> bf16 convert ----------------
__global__ __launch_bounds__(256) void f2b_kernel(const float* __restrict__ in,
                                                  unsigned short* __restrict__ out, int n) {
  int i = (blockIdx.x * 256 + threadIdx.x) * 4;
  if (i + 3 >= n) { for (int j = 0; j < 4 && i + j < n; j++) out[i + j] = f2b(in[i + j]); return; }
  float4 v = *(const float4*)(in + i);
  uint2 o;
  o.x = (unsigned)f2b(v.x) | ((unsigned)f2b(v.y) << 16);
  o.y = (unsigned)f2b(v.z) | ((unsigned)f2b(v.w) << 16);
  *(uint2*)(out + i) = o;
}

// ---------------- GEMM: C[M,N] = A[M,K] * B[N,K]^T, bf16 in/out, f32 acc ----------------
// EPI: 0 = none, 1 = +bias[n], 2 = +bias[n] then exact GELU
#define PK 40  // padded LDS row stride (elements) to break bank conflicts

template<int EPI>
__global__ __launch_bounds__(256) void gemm_bt(
    const unsigned short* __restrict__ A, const unsigned short* __restrict__ B,
    unsigned short* __restrict__ C, const float* __restrict__ bias,
    int M, int N, int K)
{
  __shared__ __align__(16) unsigned short As[128 * PK];
  __shared__ __align__(16) unsigned short Bs[128 * PK];
  const int tid = threadIdx.x;
  const int wave = tid >> 6, lane = tid & 63;
  const int lr = lane & 15, lg = lane >> 4;
  const int wm = wave >> 1, wn = wave & 1;
  const int r0 = wave * 32 + (lane >> 2);
  const int cc = (lane & 3) * 8;
  const size_t aoff0 = (size_t)(blockIdx.y * 128 + r0) * K + cc;
  const size_t aoff1 = aoff0 + (size_t)16 * K;
  const size_t boff0 = (size_t)(blockIdx.x * 128 + r0) * K + cc;
  const size_t boff1 = boff0 + (size_t)16 * K;
  const int wr0 = r0 * PK + cc, wr1 = (r0 + 16) * PK + cc;

  f32x4 acc[4][4];
  #pragma unroll
  for (int i = 0; i < 4; i++)
    #pragma unroll
    for (int j = 0; j < 4; j++) acc[i][j] = (f32x4){0.f, 0.f, 0.f, 0.f};

  for (int k0 = 0; k0 < K; k0 += 32) {
    bf16x8 ta0 = *(const bf16x8*)(A + aoff0 + k0);
    bf16x8 ta1 = *(const bf16x8*)(A + aoff1 + k0);
    bf16x8 tb0 = *(const bf16x8*)(B + boff0 + k0);
    bf16x8 tb1 = *(const bf16x8*)(B + boff1 + k0);
    __syncthreads();
    *(bf16x8*)&As[wr0] = ta0;
    *(bf16x8*)&As[wr1] = ta1;
    *(bf16x8*)&Bs[wr0] = tb0;
    *(bf16x8*)&Bs[wr1] = tb1;
    __syncthreads();
    bf16x8 af[4], bfr[4];
    #pragma unroll
    for (int mt = 0; mt < 4; mt++) af[mt] = *(const bf16x8*)&As[(wm * 64 + mt * 16 + lr) * PK + lg * 8];
    #pragma unroll
    for (int nt = 0; nt < 4; nt++) bfr[nt] = *(const bf16x8*)&Bs[(wn * 64 + nt * 16 + lr) * PK + lg * 8];
    #pragma unroll
    for (int mt = 0; mt < 4; mt++)
      #pragma unroll
      for (int nt = 0; nt < 4; nt++)
        acc[mt][nt] = __builtin_amdgcn_mfma_f32_16x16x32_bf16(af[mt], bfr[nt], acc[mt][nt], 0, 0, 0);
  }

  #pragma unroll
  for (int mt = 0; mt < 4; mt++)
    #pragma unroll
    for (int nt = 0; nt < 4; nt++) {
      const int row = blockIdx.y * 128 + wm * 64 + mt * 16 + lg * 4;
      const int col = blockIdx.x * 128 + wn * 64 + nt * 16 + lr;
      const float bv = (EPI >= 1) ? bias[col] : 0.f;
      #pragma unroll
      for (int r = 0; r < 4; r++) {
        float x = acc[mt][nt][r] + bv;
        if (EPI == 2) x = 0.5f * x * (1.f + erff(x * 0.70710678118654752f));
        C[(size_t)(row + r) * N + col] = f2b(x);
      }
    }
}

// ---------------- RoPE + reshape [M,1024] -> [B,H,S,64] ----------------
__global__ __launch_bounds__(256) void rope_kernel(
    const unsigned short* __restrict__ qp, const unsigned short* __restrict__ kp,
    unsigned short* __restrict__ qr, unsigned short* __restrict__ kr)
{
  const int gid = blockIdx.x * 4 + (threadIdx.x >> 6);  // bh*2048 + s
  const int lane = threadIdx.x & 63;
  const int s = gid & 2047;
  const int bh = gid >> 11;
  const int h = bh & 15, b = bh >> 4;
  const int j = lane & 31;
  const float inv = exp2f(-(float)j * (13.287712379549449f / 32.0f));  // 10000^(-j/32)
  float sn, cs;
  sincosf((float)s * inv, &sn, &cs);
  const size_t base = (size_t)(b * 2048 + s) * 1024 + h * 64;
  float q1 = b2f(qp[base + 2 * j]), q2 = b2f(qp[base + 2 * j + 1]);
  float k1 = b2f(kp[base + 2 * j]), k2 = b2f(kp[base + 2 * j + 1]);
  float qo = (lane < 32) ? (q1 * cs - q2 * sn) : (q1 * sn + q2 * cs);
  float ko = (lane < 32) ? (k1 * cs - k2 * sn) : (k1 * sn + k2 * cs);
  qr[(size_t)gid * 64 + lane] = f2b(qo);
  kr[(size_t)gid * 64 + lane] = f2b(ko);
}

// ---------------- V transpose: [M,1024] -> [B,H,64,S] ----------------
__global__ __launch_bounds__(256) void vtrans_kernel(
    const unsigned short* __restrict__ vp, unsigned short* __restrict__ vT)
{
  __shared__ unsigned short t[64][65];
  const int sc = blockIdx.x & 31;   // S/64 chunks
  const int bh = blockIdx.x >> 5;
  const int h = bh & 15, b = bh >> 4;
  const int tid = threadIdx.x;
  #pragma unroll
  for (int i = 0; i < 16; i++) {
    int idx = i * 256 + tid;
    int sl = idx >> 6, d = idx & 63;
    t[sl][d] = vp[(size_t)(b * 2048 + sc * 64 + sl) * 1024 + h * 64 + d];
  }
  __syncthreads();
  #pragma unroll
  for (int i = 0; i < 16; i++) {
    int idx = i * 256 + tid;
    int d = idx >> 6, sl = idx & 63;
    vT[((size_t)bh * 64 + d) * 2048 + sc * 64 + sl] = t[sl][d];
  }
}

// ---------------- Flash attention: QK^T + rel-bias + online softmax + PV ----------------
__global__ __launch_bounds__(256) void attn_kernel(
    const unsigned short* __restrict__ qr, const unsigned short* __restrict__ kr,
    const unsigned short* __restrict__ vT, const float* __restrict__ rel_tab,
    unsigned short* __restrict__ o)
{
  __shared__ float bias_s[64];
  __shared__ __align__(16) unsigned short p_lds[4][16 * 64];
  const int tid = threadIdx.x;
  const int wave = tid >> 6, lane = tid & 63;
  const int lr = lane & 15, lg = lane >> 4;
  const int bh = blockIdx.y;
  const int h = bh & 15, b = bh >> 4;
  const int q0 = blockIdx.x * 64 + wave * 16;

  if (tid < 63) bias_s[tid] = rel_tab[tid * 16 + h];
  __syncthreads();

  const unsigned short* qb = qr + (size_t)bh * 2048 * 64;
  const unsigned short* kb = kr + (size_t)bh * 2048 * 64;
  const unsigned short* vb = vT + (size_t)bh * 64 * 2048;

  bf16x8 qf[2];
  qf[0] = *(const bf16x8*)(qb + (size_t)(q0 + lr) * 64 + lg * 8);
  qf[1] = *(const bf16x8*)(qb + (size_t)(q0 + lr) * 64 + 32 + lg * 8);

  float mrow[4], lrow[4];
  #pragma unroll
  for (int r = 0; r < 4; r++) { mrow[r] = -1e30f; lrow[r] = 0.f; }
  f32x4 oacc[4];
  #pragma unroll
  for (int nt = 0; nt < 4; nt++) oacc[nt] = (f32x4){0.f, 0.f, 0.f, 0.f};

  unsigned short* pw = &p_lds[wave][0];

  for (int k0 = 0; k0 < 2048; k0 += 64) {
    f32x4 sacc[4];
    #pragma unroll
    for (int nt = 0; nt < 4; nt++) sacc[nt] = (f32x4){0.f, 0.f, 0.f, 0.f};
    #pragma unroll
    for (int nt = 0; nt < 4; nt++) {
      #pragma unroll
      for (int ks = 0; ks < 2; ks++) {
        bf16x8 kf = *(const bf16x8*)(kb + (size_t)(k0 + nt * 16 + lr) * 64 + ks * 32 + lg * 8);
        sacc[nt] = __builtin_amdgcn_mfma_f32_16x16x32_bf16(qf[ks], kf, sacc[nt], 0, 0, 0);
      }
    }
    // scale + relative-position bias
    float sv[4][4];
    #pragma unroll
    for (int nt = 0; nt < 4; nt++)
      #pragma unroll
      for (int r = 0; r < 4; r++) {
        int qa = q0 + lg * 4 + r;
        int ka = k0 + nt * 16 + lr;
        int d = qa - ka; d = d < -31 ? -31 : (d > 31 ? 31 : d);
        sv[nt][r] = sacc[nt][r] * 0.125f + bias_s[d + 31];
      }
    // online softmax (rows live across 16 lanes of an lg-group)
    #pragma unroll
    for (int r = 0; r < 4; r++) {
      float rm = fmaxf(fmaxf(sv[0][r], sv[1][r]), fmaxf(sv[2][r], sv[3][r]));
      rm = fmaxf(rm, __shfl_xor(rm, 1));
      rm = fmaxf(rm, __shfl_xor(rm, 2));
      rm = fmaxf(rm, __shfl_xor(rm, 4));
      rm = fmaxf(rm, __shfl_xor(rm, 8));
      float mnew = fmaxf(mrow[r], rm);
      float scale = __expf(mrow[r] - mnew);
      float rs = 0.f;
      #pragma unroll
      for (int nt = 0; nt < 4; nt++) { float p = __expf(sv[nt][r] - mnew); sv[nt][r] = p; rs += p; }
      rs += __shfl_xor(rs, 1); rs += __shfl_xor(rs, 2); rs += __shfl_xor(rs, 4); rs += __shfl_xor(rs, 8);
      lrow[r] = lrow[r] * scale + rs;
      mrow[r] = mnew;
      #pragma unroll
      for (int nt = 0; nt < 4; nt++) oacc[nt][r] *= scale;
    }
    // stage P (bf16) through per-wave LDS, XOR-swizzled to kill read conflicts
    #pragma unroll
    for (int nt = 0; nt < 4; nt++)
      #pragma unroll
      for (int r = 0; r < 4; r++) {
        int row = lg * 4 + r;
        int col = nt * 16 + lr;
        pw[row * 64 + (col ^ ((row & 7) << 3))] = f2b(sv[nt][r]);
      }
    asm volatile("s_waitcnt lgkmcnt(0)" ::: "memory");
    // P @ V
    #pragma unroll
    for (int ks = 0; ks < 2; ks++) {
      bf16x8 pf = *(const bf16x8*)(pw + lr * 64 + ((ks * 32 + lg * 8) ^ ((lr & 7) << 3)));
      #pragma unroll
      for (int nt = 0; nt < 4; nt++) {
        bf16x8 vf = *(const bf16x8*)(vb + (size_t)(nt * 16 + lr) * 2048 + k0 + ks * 32 + lg * 8);
        oacc[nt] = __builtin_amdgcn_mfma_f32_16x16x32_bf16(pf, vf, oacc[nt], 0, 0, 0);
      }
    }
    asm volatile("s_waitcnt lgkmcnt(0)" ::: "memory");
  }
  // epilogue: divide by l, scatter to [M, 1024]
  #pragma unroll
  for (int nt = 0; nt < 4; nt++)
    #pragma unroll
    for (int r = 0; r < 4; r++) {
      int qa = q0 + lg * 4 + r;
      int d = nt * 16 + lr;
      float outv = oacc[nt][r] / lrow[r];
      o[(size_t)(b * 2048 + qa) * 1024 + h * 64 + d] = f2b(outv);
    }
}

// ---------------- LayerNorm 1: h = LN(x + ao), write bf16 ----------------
__global__ __launch_bounds__(256) void ln1_kernel(
    const float* __restrict__ x, const unsigned short* __restrict__ ao,
    const float* __restrict__ g, const float* __restrict__ bta,
    unsigned short* __restrict__ hb)
{
  const int row = blockIdx.x, tid = threadIdx.x;
  const int wave = tid >> 6, lane = tid & 63;
  float v[4]; float s = 0.f, s2 = 0.f;
  #pragma unroll
  for (int j = 0; j < 4; j++) {
    int c = tid + j * 256;
    float t = x[(size_t)row * 1024 + c] + b2f(ao[(size_t)row * 1024 + c]);
    v[j] = t; s += t; s2 += t * t;
  }
  #pragma unroll
  for (int off = 32; off >= 1; off >>= 1) { s += __shfl_down(s, off); s2 += __shfl_down(s2, off); }
  __shared__ float rs[4], rs2[4];
  if (lane == 0) { rs[wave] = s; rs2[wave] = s2; }
  __syncthreads();
  s = rs[0] + rs[1] + rs[2] + rs[3];
  s2 = rs2[0] + rs2[1] + rs2[2] + rs2[3];
  float mean = s * (1.f / 1024.f);
  float var = s2 * (1.f / 1024.f) - mean * mean;
  float inv = rsqrtf(var + 1e-5f);
  #pragma unroll
  for (int j = 0; j < 4; j++) {
    int c = tid + j * 256;
    hb[(size_t)row * 1024 + c] = f2b((v[j] - mean) * inv * g[c] + bta[c]);
  }
}

// ---------------- LayerNorm 2: out = LN(hb + fb), write f32 ----------------
__global__ __launch_bounds__(256) void ln2_kernel(
    const unsigned short* __restrict__ hb, const unsigned short* __restrict__ fb,
    const float* __restrict__ g, const float* __restrict__ bta,
    float* __restrict__ out)
{
  const int row = blockIdx.x, tid = threadIdx.x;
  const int wave = tid >> 6, lane = tid & 63;
  float v[4]; float s = 0.f, s2 = 0.f;
  #pragma unroll
  for (int j = 0; j < 4; j++) {
    int c = tid + j * 256;
    float t = b2f(hb[(size_t)row * 1024 + c]) + b2f(fb[(size_t)row * 1024 + c]);
    v[j] = t; s += t; s2 += t * t;
  }
  #pragma unroll
  for (int off = 32; off >= 1; off >>= 1) { s += __shfl_down(s, off); s2 += __shfl_down(s2, off); }
  __shared__ float rs[4], rs2[4];
  if (lane == 0) { rs[wave] = s; rs2[wave] = s2; }
  __syncthreads();
  s = rs[0] + rs[1] + rs[2] + rs[3];
  s2 = rs2[0] + rs2[1] + rs2[2] + rs2[3];
  float mean = s * (1.f / 1024.f);
  float var = s2 * (1.f / 1024.f) - mean * mean;
  float inv = rsqrtf(var + 1e-5f);
  #pragma unroll
  for (int j = 0; j < 4; j++) {
    int c = tid + j * 256;
    out[(size_t)row * 1024 + c] = (v[j] - mean) * inv * g[c] + bta[c];
  }
}

// ---------------- host launcher ----------------
extern "C" void kernel_launch(void* const* d_in, const int* in_sizes, int n_in,
                              void* d_out, int out_size, void* d_ws, size_t ws_size,
                              hipStream_t stream)
{
  const float* x    = (const float*)d_in[0];
  const float* wq   = (const float*)d_in[1];
  const float* wk   = (const float*)d_in[2];
  const float* wv   = (const float*)d_in[3];
  const float* wo   = (const float*)d_in[4];
  const float* wo_b = (const float*)d_in[5];
  const float* rel  = (const float*)d_in[6];
  const float* ln1g = (const float*)d_in[7];
  const float* ln1b = (const float*)d_in[8];
  const float* ln2g = (const float*)d_in[9];
  const float* ln2b = (const float*)d_in[10];
  const float* w1   = (const float*)d_in[11];
  const float* b1   = (const float*)d_in[12];
  const float* w2   = (const float*)d_in[13];
  const float* b2   = (const float*)d_in[14];
  float* out = (float*)d_out;
  char* w = (char*)d_ws;

  if (ws_size < (size_t)112 * MB) return;

  unsigned short* xb  = (unsigned short*)(w + (size_t)0 * MB);   // 8MB
  unsigned short* wqb = (unsigned short*)(w + (size_t)8 * MB);   // 2MB
  unsigned short* wkb = (unsigned short*)(w + (size_t)10 * MB);  // 2MB
  unsigned short* wvb = (unsigned short*)(w + (size_t)12 * MB);  // 2MB
  unsigned short* wob = (unsigned short*)(w + (size_t)14 * MB);  // 2MB
  unsigned short* w1b = (unsigned short*)(w + (size_t)16 * MB);  // 8MB
  unsigned short* w2b = (unsigned short*)(w + (size_t)24 * MB);  // 8MB
  unsigned short* qp  = (unsigned short*)(w + (size_t)32 * MB);  // 8MB (reused: attn out o)
  unsigned short* kp  = (unsigned short*)(w + (size_t)40 * MB);  // 8MB (reused: ao)
  unsigned short* vp  = (unsigned short*)(w + (size_t)48 * MB);  // 8MB (reused: hb)
  unsigned short* qrb = (unsigned short*)(w + (size_t)56 * MB);  // 8MB (reused: fb)
  unsigned short* krb = (unsigned short*)(w + (size_t)64 * MB);  // 8MB
  unsigned short* vTb = (unsigned short*)(w + (size_t)72 * MB);  // 8MB
  unsigned short* gb  = (unsigned short*)(w + (size_t)80 * MB);  // 32MB

  const int M = 4096, D = 1024, F = 4096;

  // converts
  f2b_kernel<<<dim3(M * D / 1024), 256, 0, stream>>>(x, xb, M * D);
  f2b_kernel<<<dim3(D * D / 1024), 256, 0, stream>>>(wq, wqb, D * D);
  f2b_kernel<<<dim3(D * D / 1024), 256, 0, stream>>>(wk, wkb, D * D);
  f2b_kernel<<<dim3(D * D / 1024), 256, 0, stream>>>(wv, wvb, D * D);
  f2b_kernel<<<dim3(D * D / 1024), 256, 0, stream>>>(wo, wob, D * D);
  f2b_kernel<<<dim3(F * D / 1024), 256, 0, stream>>>(w1, w1b, F * D);
  f2b_kernel<<<dim3(D * F / 1024), 256, 0, stream>>>(w2, w2b, D * F);

  // QKV projections
  gemm_bt<0><<<dim3(D / 128, M / 128), 256, 0, stream>>>(xb, wqb, qp, nullptr, M, D, D);
  gemm_bt<0><<<dim3(D / 128, M / 128), 256, 0, stream>>>(xb, wkb, kp, nullptr, M, D, D);
  gemm_bt<0><<<dim3(D / 128, M / 128), 256, 0, stream>>>(xb, wvb, vp, nullptr, M, D, D);

  // RoPE + reshape, V transpose
  rope_kernel<<<dim3(16384), 256, 0, stream>>>(qp, kp, qrb, krb);
  vtrans_kernel<<<dim3(1024), 256, 0, stream>>>(vp, vTb);

  // attention -> o (reuses qp)
  attn_kernel<<<dim3(32, 32), 256, 0, stream>>>(qrb, krb, vTb, rel, qp);

  // out projection (+wo_b) -> ao (reuses kp)
  gemm_bt<1><<<dim3(D / 128, M / 128), 256, 0, stream>>>(qp, wob, kp, wo_b, M, D, D);

  // ln1: h = LN(x + ao) -> hb (reuses vp)
  ln1_kernel<<<dim3(M), 256, 0, stream>>>(x, kp, ln1g, ln1b, vp);

  // FFN1 (+b1, gelu) -> gb
  gemm_bt<2><<<dim3(F / 128, M / 128), 256, 0, stream>>>(vp, w1b, gb, b1, M, F, D);

  // FFN2 (+b2) -> fb (reuses qrb)
  gemm_bt<1><<<dim3(D / 128, M / 128), 256, 0, stream>>>(gb, w2b, qrb, b2, M, D, F);

  // ln2: out = LN(h + f) -> d_out (f32)
  ln2_kernel<<<dim3(M), 256, 0, stream>>>(vp, qrb, ln2g, ln2b, out);
}

// Round 2
// 311.313 us; speedup vs baseline: 1.7493x; 1.7493x over previous
//
#include <hip/hip_runtime.h>
#include <stdint.h>

#define MB (1ull << 20)
typedef unsigned short u16;
typedef __attribute__((ext_vector_type(8))) short bf16x8;
typedef __attribute__((ext_vector_type(4))) float f32x4;

__device__ __forceinline__ float b2f(u16 u) {
  union { unsigned int i; float f; } c; c.i = ((unsigned int)u) << 16; return c.f;
}
__device__ __forceinline__ u16 f2b(float f) {
  union { float f; unsigned int i; } c; c.f = f;
  unsigned int r = c.i + 0x7fffu + ((c.i >> 16) & 1u);
  return (u16)(r >> 16);
}
__device__ __forceinline__ void gload16(const void* g, void* l) {
  __builtin_amdgcn_global_load_lds(
      (const __attribute__((address_space(1))) void*)g,
      (__attribute__((address_space(3))) void*)l, 16, 0, 0);
}

// ---------------- f32 -> bf16 convert ----------------
__global__ __launch_bounds__(256) void f2b_kernel(const float* __restrict__ in,
                                                  u16* __restrict__ out, int n) {
  int i = (blockIdx.x * 256 + threadIdx.x) * 4;
  if (i + 3 >= n) { for (int j = 0; j < 4 && i + j < n; j++) out[i + j] = f2b(in[i + j]); return; }
  float4 v = *(const float4*)(in + i);
  uint2 o;
  o.x = (unsigned)f2b(v.x) | ((unsigned)f2b(v.y) << 16);
  o.y = (unsigned)f2b(v.z) | ((unsigned)f2b(v.w) << 16);
  *(uint2*)(out + i) = o;
}

// ---------------- GEMM: C[M,N] = A[M,K] * B[N,K]^T, bf16, f32 acc ----------------
// m97 structure: BK=64, global_load_lds width-16, both-sides XOR swizzle.
// EPI: 0=none, 1=+bias, 2=+bias+GELU.  BM: 128 (4x4 acc/wave) or 64 (2x4).
template<int EPI, int BM>
__global__ __launch_bounds__(256) void gemm_bt(
    const u16* __restrict__ A, const u16* __restrict__ B,
    u16* __restrict__ C, const float* __restrict__ bias,
    int M, int N, int K)
{
  constexpr int MT = BM / 32;  // 4 or 2
  __shared__ __align__(16) u16 As[BM * 64];
  __shared__ __align__(16) u16 Bs[128 * 64];
  const int tid = threadIdx.x;
  const int lane = tid & 63, wave = tid >> 6;
  const int lr = lane & 15, lg = lane >> 4;
  const int wm = wave >> 1, wn = wave & 1;

  // bijective XCD-chunked block swizzle (all grids are %8==0)
  const int nwg = gridDim.x * gridDim.y;
  const int id = blockIdx.y * gridDim.x + blockIdx.x;
  const int nid = (id & 7) * (nwg >> 3) + (id >> 3);
  const int bx = nid % gridDim.x, by = nid / gridDim.x;

  // staging: thread covers tile row srow(+32h), 8 elems at swizzled col
  const int srow = tid >> 3;
  const int scsw = ((tid & 7) * 8) ^ ((srow & 7) << 3);
  const size_t abase = (size_t)(by * BM + srow) * K + scsw;
  const size_t bbase = (size_t)(bx * 128 + srow) * K + scsw;

  // fragment read offsets (elements), loop-invariant
  int aoff[MT][2], boff[4][2];
  #pragma unroll
  for (int mt = 0; mt < MT; mt++) {
    int row = wm * (BM / 2) + mt * 16 + lr;
    #pragma unroll
    for (int kk = 0; kk < 2; kk++)
      aoff[mt][kk] = row * 64 + ((kk * 32 + lg * 8) ^ ((row & 7) << 3));
  }
  #pragma unroll
  for (int nt = 0; nt < 4; nt++) {
    int row = wn * 64 + nt * 16 + lr;
    #pragma unroll
    for (int kk = 0; kk < 2; kk++)
      boff[nt][kk] = row * 64 + ((kk * 32 + lg * 8) ^ ((row & 7) << 3));
  }

  f32x4 acc[MT][4];
  #pragma unroll
  for (int i = 0; i < MT; i++)
    #pragma unroll
    for (int j = 0; j < 4; j++) acc[i][j] = (f32x4){0.f, 0.f, 0.f, 0.f};

  for (int k0 = 0; k0 < K; k0 += 64) {
    __syncthreads();  // prior ds_reads done before overwrite
    #pragma unroll
    for (int h = 0; h < MT; h++)
      gload16(A + abase + (size_t)(h * 32) * K + k0, &As[h * 2048 + tid * 8]);
    #pragma unroll
    for (int h = 0; h < 4; h++)
      gload16(B + bbase + (size_t)(h * 32) * K + k0, &Bs[h * 2048 + tid * 8]);
    __syncthreads();  // compiler drains vmcnt before barrier -> tiles ready
    #pragma unroll
    for (int kk = 0; kk < 2; kk++) {
      bf16x8 af[MT], bfr[4];
      #pragma unroll
      for (int mt = 0; mt < MT; mt++) af[mt] = *(const bf16x8*)&As[aoff[mt][kk]];
      #pragma unroll
      for (int nt = 0; nt < 4; nt++) bfr[nt] = *(const bf16x8*)&Bs[boff[nt][kk]];
      #pragma unroll
      for (int mt = 0; mt < MT; mt++)
        #pragma unroll
        for (int nt = 0; nt < 4; nt++)
          acc[mt][nt] = __builtin_amdgcn_mfma_f32_16x16x32_bf16(af[mt], bfr[nt], acc[mt][nt], 0, 0, 0);
    }
  }

  #pragma unroll
  for (int mt = 0; mt < MT; mt++)
    #pragma unroll
    for (int nt = 0; nt < 4; nt++) {
      const int row = by * BM + wm * (BM / 2) + mt * 16 + lg * 4;
      const int col = bx * 128 + wn * 64 + nt * 16 + lr;
      const float bv = (EPI >= 1) ? bias[col] : 0.f;
      #pragma unroll
      for (int r = 0; r < 4; r++) {
        float x = acc[mt][nt][r] + bv;
        if (EPI == 2) x = 0.5f * x * (1.f + erff(x * 0.70710678118654752f));
        C[(size_t)(row + r) * N + col] = f2b(x);
      }
    }
}

// ---------------- RoPE + reshape [M,stride] -> [B,H,S,64] ----------------
__global__ __launch_bounds__(256) void rope_kernel(
    const u16* __restrict__ qp, const u16* __restrict__ kp, int stride,
    u16* __restrict__ qr, u16* __restrict__ kr)
{
  const int gid = blockIdx.x * 4 + (threadIdx.x >> 6);
  const int lane = threadIdx.x & 63;
  const int s = gid & 2047;
  const int bh = gid >> 11;
  const int h = bh & 15, b = bh >> 4;
  const int j = lane & 31;
  const float inv = exp2f(-(float)j * (13.287712379549449f / 32.0f));
  float sn, cs;
  sincosf((float)s * inv, &sn, &cs);
  const size_t base = (size_t)(b * 2048 + s) * stride + h * 64;
  float q1 = b2f(qp[base + 2 * j]), q2 = b2f(qp[base + 2 * j + 1]);
  float k1 = b2f(kp[base + 2 * j]), k2 = b2f(kp[base + 2 * j + 1]);
  float qo = (lane < 32) ? (q1 * cs - q2 * sn) : (q1 * sn + q2 * cs);
  float ko = (lane < 32) ? (k1 * cs - k2 * sn) : (k1 * sn + k2 * cs);
  qr[(size_t)gid * 64 + lane] = f2b(qo);
  kr[(size_t)gid * 64 + lane] = f2b(ko);
}

// ---------------- V transpose: [M,stride] -> [B,H,64,S] ----------------
__global__ __launch_bounds__(256) void vtrans_kernel(
    const u16* __restrict__ vp, int stride, u16* __restrict__ vT)
{
  __shared__ u16 t[64][65];
  const int sc = blockIdx.x & 31;
  const int bh = blockIdx.x >> 5;
  const int h = bh & 15, b = bh >> 4;
  const int tid = threadIdx.x;
  #pragma unroll
  for (int i = 0; i < 16; i++) {
    int idx = i * 256 + tid;
    int sl = idx >> 6, d = idx & 63;
    t[sl][d] = vp[(size_t)(b * 2048 + sc * 64 + sl) * stride + h * 64 + d];
  }
  __syncthreads();
  #pragma unroll
  for (int i = 0; i < 16; i++) {
    int idx = i * 256 + tid;
    int d = idx >> 6, sl = idx & 63;
    vT[((size_t)bh * 64 + d) * 2048 + sc * 64 + sl] = t[sl][d];
  }
}

// ---------------- Flash attention, LDS-staged K/V ----------------
__global__ __launch_bounds__(256) void attn_kernel(
    const u16* __restrict__ qr, const u16* __restrict__ kr,
    const u16* __restrict__ vT, const float* __restrict__ rel_tab,
    u16* __restrict__ o)
{
  __shared__ __align__(16) u16 Ks[64 * 64];
  __shared__ __align__(16) u16 Vs[64 * 64];
  __shared__ __align__(16) u16 Ps[4][16 * 64];
  __shared__ float bias_s[64];

  const int tid = threadIdx.x;
  const int lane = tid & 63, wave = tid >> 6;
  const int lr = lane & 15, lg = lane >> 4;

  const int id = blockIdx.x;               // 1024 blocks
  const int nid = (id & 7) * 128 + (id >> 3);
  const int bh = nid >> 5, qc = nid & 31;  // same-bh blocks contiguous per XCD
  const int h = bh & 15, b = bh >> 4;
  const int q0 = qc * 64 + wave * 16;

  if (tid < 63) bias_s[tid] = rel_tab[tid * 16 + h] * 1.4426950408889634f;

  const u16* qb = qr + (size_t)bh * 2048 * 64;
  const u16* kb = kr + (size_t)bh * 2048 * 64;
  const u16* vb = vT + (size_t)bh * 64 * 2048;

  bf16x8 qf[2];
  qf[0] = *(const bf16x8*)(qb + (size_t)(q0 + lr) * 64 + lg * 8);
  qf[1] = *(const bf16x8*)(qb + (size_t)(q0 + lr) * 64 + 32 + lg * 8);

  const int srow = tid >> 3;
  const int scsw = ((tid & 7) * 8) ^ ((srow & 7) << 3);

  int koff[4][2], poff[2];
  #pragma unroll
  for (int nt = 0; nt < 4; nt++)
    #pragma unroll
    for (int ks = 0; ks < 2; ks++)
      koff[nt][ks] = (nt * 16 + lr) * 64 + ((ks * 32 + lg * 8) ^ ((lr & 7) << 3));
  #pragma unroll
  for (int ks = 0; ks < 2; ks++)
    poff[ks] = lr * 64 + ((ks * 32 + lg * 8) ^ ((lr & 7) << 3));

  float mrow[4], lpart[4];
  #pragma unroll
  for (int r = 0; r < 4; r++) { mrow[r] = -1e30f; lpart[r] = 0.f; }
  f32x4 oacc[4];
  #pragma unroll
  for (int nt = 0; nt < 4; nt++) oacc[nt] = (f32x4){0.f, 0.f, 0.f, 0.f};

  const float SC = 0.18033688011112042f;  // 0.125 * log2(e)

  for (int kc = 0; kc < 32; kc++) {
    const int k0 = kc * 64;
    __syncthreads();  // prior chunk's LDS reads done
    #pragma unroll
    for (int hh = 0; hh < 2; hh++) {
      gload16(kb + (size_t)(k0 + hh * 32 + srow) * 64 + scsw, &Ks[hh * 2048 + tid * 8]);
      gload16(vb + (size_t)(hh * 32 + srow) * 2048 + k0 + scsw, &Vs[hh * 2048 + tid * 8]);
    }
    __syncthreads();  // vmcnt drained -> tiles ready

    f32x4 sacc[4];
    #pragma unroll
    for (int nt = 0; nt < 4; nt++) sacc[nt] = (f32x4){0.f, 0.f, 0.f, 0.f};
    #pragma unroll
    for (int ks = 0; ks < 2; ks++)
      #pragma unroll
      for (int nt = 0; nt < 4; nt++) {
        bf16x8 kf = *(const bf16x8*)&Ks[koff[nt][ks]];
        sacc[nt] = __builtin_amdgcn_mfma_f32_16x16x32_bf16(qf[ks], kf, sacc[nt], 0, 0, 0);
      }

    // scale (log2 domain) + rel bias; wave-uniform fast path off-diagonal
    float sv[4][4];
    const int dmin = q0 - k0 - 63, dmax = q0 + 15 - k0;
    if (dmin >= 31 || dmax <= -31) {
      const float c = bias_s[dmin >= 31 ? 62 : 0];
      #pragma unroll
      for (int nt = 0; nt < 4; nt++)
        #pragma unroll
        for (int r = 0; r < 4; r++) sv[nt][r] = sacc[nt][r] * SC + c;
    } else {
      #pragma unroll
      for (int nt = 0; nt < 4; nt++)
        #pragma unroll
        for (int r = 0; r < 4; r++) {
          int d = (q0 + lg * 4 + r) - (k0 + nt * 16 + lr);
          d = d < -31 ? -31 : (d > 31 ? 31 : d);
          sv[nt][r] = sacc[nt][r] * SC + bias_s[d + 31];
        }
    }

    // row max across the 16 lr-lanes
    float rm[4];
    #pragma unroll
    for (int r = 0; r < 4; r++) {
      float m = fmaxf(fmaxf(sv[0][r], sv[1][r]), fmaxf(sv[2][r], sv[3][r]));
      m = fmaxf(m, __shfl_xor(m, 1));
      m = fmaxf(m, __shfl_xor(m, 2));
      m = fmaxf(m, __shfl_xor(m, 4));
      m = fmaxf(m, __shfl_xor(m, 8));
      rm[r] = m;
    }
    // defer-max (T13): skip rescale when max growth <= 8 nats (11.5 in log2)
    int defer = (rm[0] <= mrow[0] + 11.5f) & (rm[1] <= mrow[1] + 11.5f) &
                (rm[2] <= mrow[2] + 11.5f) & (rm[3] <= mrow[3] + 11.5f);
    if (!__all(defer)) {
      #pragma unroll
      for (int r = 0; r < 4; r++) {
        float mnew = fmaxf(mrow[r], rm[r]);
        float sc = exp2f(mrow[r] - mnew);
        lpart[r] *= sc;
        #pragma unroll
        for (int nt = 0; nt < 4; nt++) oacc[nt][r] *= sc;
        mrow[r] = mnew;
      }
    }
    // exp2 + per-lane partial l-sum (reduced once in epilogue) + P to LDS
    #pragma unroll
    for (int r = 0; r < 4; r++) {
      const int prow = lg * 4 + r;
      const int sw = (prow & 7) << 3;
      #pragma unroll
      for (int nt = 0; nt < 4; nt++) {
        float p = exp2f(sv[nt][r] - mrow[r]);
        lpart[r] += p;
        Ps[wave][prow * 64 + ((nt * 16 + lr) ^ sw)] = f2b(p);
      }
    }
    // P @ V (per-wave LDS, compiler orders lgkmcnt)
    #pragma unroll
    for (int ks = 0; ks < 2; ks++) {
      bf16x8 pf = *(const bf16x8*)&Ps[wave][poff[ks]];
      #pragma unroll
      for (int nt = 0; nt < 4; nt++) {
        bf16x8 vf = *(const bf16x8*)&Vs[koff[nt][ks]];
        oacc[nt] = __builtin_amdgcn_mfma_f32_16x16x32_bf16(pf, vf, oacc[nt], 0, 0, 0);
      }
    }
  }

  #pragma unroll
  for (int r = 0; r < 4; r++) {
    float l = lpart[r];
    l += __shfl_xor(l, 1); l += __shfl_xor(l, 2);
    l += __shfl_xor(l, 4); l += __shfl_xor(l, 8);
    lpart[r] = 1.0f / l;
  }
  #pragma unroll
  for (int nt = 0; nt < 4; nt++)
    #pragma unroll
    for (int r = 0; r < 4; r++) {
      int qa = q0 + lg * 4 + r;
      int d = nt * 16 + lr;
      o[(size_t)(b * 2048 + qa) * 1024 + h * 64 + d] = f2b(oacc[nt][r] * lpart[r]);
    }
}

// ---------------- LayerNorm 1: h = LN(x + ao), bf16 out ----------------
__global__ __launch_bounds__(256) void ln1_kernel(
    const float* __restrict__ x, const u16* __restrict__ ao,
    const float* __restrict__ g, const float* __restrict__ bta,
    u16* __restrict__ hb)
{
  const int row = blockIdx.x, tid = threadIdx.x;
  const int wave = tid >> 6, lane = tid & 63;
  float v[4]; float s = 0.f, s2 = 0.f;
  #pragma unroll
  for (int j = 0; j < 4; j++) {
    int c = tid + j * 256;
    float t = x[(size_t)row * 1024 + c] + b2f(ao[(size_t)row * 1024 + c]);
    v[j] = t; s += t; s2 += t * t;
  }
  #pragma unroll
  for (int off = 32; off >= 1; off >>= 1) { s += __shfl_down(s, off); s2 += __shfl_down(s2, off); }
  __shared__ float rs[4], rs2[4];
  if (lane == 0) { rs[wave] = s; rs2[wave] = s2; }
  __syncthreads();
  s = rs[0] + rs[1] + rs[2] + rs[3];
  s2 = rs2[0] + rs2[1] + rs2[2] + rs2[3];
  float mean = s * (1.f / 1024.f);
  float var = s2 * (1.f / 1024.f) - mean * mean;
  float inv = rsqrtf(var + 1e-5f);
  #pragma unroll
  for (int j = 0; j < 4; j++) {
    int c = tid + j * 256;
    hb[(size_t)row * 1024 + c] = f2b((v[j] - mean) * inv * g[c] + bta[c]);
  }
}

// ---------------- LayerNorm 2: out = LN(hb + fb), f32 out ----------------
__global__ __launch_bounds__(256) void ln2_kernel(
    const u16* __restrict__ hb, const u16* __restrict__ fb,
    const float* __restrict__ g, const float* __restrict__ bta,
    float* __restrict__ out)
{
  const int row = blockIdx.x, tid = threadIdx.x;
  const int wave = tid >> 6, lane = tid & 63;
  float v[4]; float s = 0.f, s2 = 0.f;
  #pragma unroll
  for (int j = 0; j < 4; j++) {
    int c = tid + j * 256;
    float t = b2f(hb[(size_t)row * 1024 + c]) + b2f(fb[(size_t)row * 1024 + c]);
    v[j] = t; s += t; s2 += t * t;
  }
  #pragma unroll
  for (int off = 32; off >= 1; off >>= 1) { s += __shfl_down(s, off); s2 += __shfl_down(s2, off); }
  __shared__ float rs[4], rs2[4];
  if (lane == 0) { rs[wave] = s; rs2[wave] = s2; }
  __syncthreads();
  s = rs[0] + rs[1] + rs[2] + rs[3];
  s2 = rs2[0] + rs2[1] + rs2[2] + rs2[3];
  float mean = s * (1.f / 1024.f);
  float var = s2 * (1.f / 1024.f) - mean * mean;
  float inv = rsqrtf(var + 1e-5f);
  #pragma unroll
  for (int j = 0; j < 4; j++) {
    int c = tid + j * 256;
    out[(size_t)row * 1024 + c] = (v[j] - mean) * inv * g[c] + bta[c];
  }
}

// ---------------- host launcher ----------------
extern "C" void kernel_launch(void* const* d_in, const int* in_sizes, int n_in,
                              void* d_out, int out_size, void* d_ws, size_t ws_size,
                              hipStream_t stream)
{
  const float* x    = (const float*)d_in[0];
  const float* wq   = (const float*)d_in[1];
  const float* wk   = (const float*)d_in[2];
  const float* wv   = (const float*)d_in[3];
  const float* wo   = (const float*)d_in[4];
  const float* wo_b = (const float*)d_in[5];
  const float* rel  = (const float*)d_in[6];
  const float* ln1g = (const float*)d_in[7];
  const float* ln1b = (const float*)d_in[8];
  const float* ln2g = (const float*)d_in[9];
  const float* ln2b = (const float*)d_in[10];
  const float* w1   = (const float*)d_in[11];
  const float* b1   = (const float*)d_in[12];
  const float* w2   = (const float*)d_in[13];
  const float* b2   = (const float*)d_in[14];
  float* out = (float*)d_out;
  char* w = (char*)d_ws;

  if (ws_size < (size_t)90 * MB) return;

  // layout (MB): [xb 0-8][wqkv 8-14][wob 14-16][w1b 16-24][w2b 24-32]
  //              [qkv 32-56 -> o@32 ao@40 hb@48][qrb 56][krb 64][vTb 72]
  //              gb = 56-88 (reuses qrb/krb/vTb after attn); fb = 0-8 (reuses xb)
  u16* xb    = (u16*)(w + 0 * MB);
  u16* wqkvb = (u16*)(w + 8 * MB);
  u16* wob   = (u16*)(w + 14 * MB);
  u16* w1b   = (u16*)(w + 16 * MB);
  u16* w2b   = (u16*)(w + 24 * MB);
  u16* qkv   = (u16*)(w + 32 * MB);
  u16* ob    = (u16*)(w + 32 * MB);
  u16* ao    = (u16*)(w + 40 * MB);
  u16* hb    = (u16*)(w + 48 * MB);
  u16* qrb   = (u16*)(w + 56 * MB);
  u16* krb   = (u16*)(w + 64 * MB);
  u16* vTb   = (u16*)(w + 72 * MB);
  u16* gb    = (u16*)(w + 56 * MB);
  u16* fb    = (u16*)(w + 0 * MB);

  const int M = 4096, D = 1024, F = 4096;

  f2b_kernel<<<dim3(M * D / 1024), 256, 0, stream>>>(x, xb, M * D);
  f2b_kernel<<<dim3(D * D / 1024), 256, 0, stream>>>(wq, wqkvb, D * D);
  f2b_kernel<<<dim3(D * D / 1024), 256, 0, stream>>>(wk, wqkvb + D * D, D * D);
  f2b_kernel<<<dim3(D * D / 1024), 256, 0, stream>>>(wv, wqkvb + 2 * D * D, D * D);
  f2b_kernel<<<dim3(D * D / 1024), 256, 0, stream>>>(wo, wob, D * D);
  f2b_kernel<<<dim3(F * D / 1024), 256, 0, stream>>>(w1, w1b, F * D);
  f2b_kernel<<<dim3(D * F / 1024), 256, 0, stream>>>(w2, w2b, D * F);

  // fused QKV projection: [4096, 3072]
  gemm_bt<0, 128><<<dim3(3 * D / 128, M / 128), 256, 0, stream>>>(xb, wqkvb, qkv, nullptr, M, 3 * D, D);

  rope_kernel<<<dim3(16384), 256, 0, stream>>>(qkv, qkv + 1024, 3 * D, qrb, krb);
  vtrans_kernel<<<dim3(1024), 256, 0, stream>>>(qkv + 2048, 3 * D, vTb);

  attn_kernel<<<dim3(1024), 256, 0, stream>>>(qrb, krb, vTb, rel, ob);

  gemm_bt<1, 64><<<dim3(D / 128, M / 64), 256, 0, stream>>>(ob, wob, ao, wo_b, M, D, D);

  ln1_kernel<<<dim3(M), 256, 0, stream>>>(x, ao, ln1g, ln1b, hb);

  gemm_bt<2, 128><<<dim3(F / 128, M / 128), 256, 0, stream>>>(hb, w1b, gb, b1, M, F, D);

  gemm_bt<1, 64><<<dim3(D / 128, M / 64), 256, 0, stream>>>(gb, w2b, fb, b2, M, D, F);

  ln2_kernel<<<dim3(M), 256, 0, stream>>>(hb, fb, ln2g, ln2b, out);
}

// Round 3
// 290.669 us; speedup vs baseline: 1.8735x; 1.0710x over previous
//
#include <hip/hip_runtime.h>
#include <stdint.h>

#define MB (1ull << 20)
typedef unsigned short u16;
typedef __attribute__((ext_vector_type(8))) short bf16x8;
typedef __attribute__((ext_vector_type(4))) float f32x4;

__device__ __forceinline__ float b2f(u16 u) {
  union { unsigned int i; float f; } c; c.i = ((unsigned int)u) << 16; return c.f;
}
__device__ __forceinline__ u16 f2b(float f) {
  union { float f; unsigned int i; } c; c.f = f;
  unsigned int r = c.i + 0x7fffu + ((c.i >> 16) & 1u);
  return (u16)(r >> 16);
}
__device__ __forceinline__ void gload16(const void* g, void* l) {
  __builtin_amdgcn_global_load_lds(
      (const __attribute__((address_space(1))) void*)g,
      (__attribute__((address_space(3))) void*)l, 16, 0, 0);
}

// ---------------- fused f32 -> bf16 convert (all tensors, one launch) ----------------
__global__ __launch_bounds__(256) void f2b_all(
    const float* __restrict__ x, const float* __restrict__ wq, const float* __restrict__ wk,
    const float* __restrict__ wv, const float* __restrict__ wo, const float* __restrict__ w1,
    const float* __restrict__ w2,
    u16* __restrict__ xb, u16* __restrict__ wqkvb, u16* __restrict__ wob,
    u16* __restrict__ w1b, u16* __restrict__ w2b)
{
  int bid = blockIdx.x;
  const float* src; u16* dst;
  if (bid < 4096)       { src = x;  dst = xb; }
  else if (bid < 5120)  { src = wq; dst = wqkvb;           bid -= 4096; }
  else if (bid < 6144)  { src = wk; dst = wqkvb + 1048576; bid -= 5120; }
  else if (bid < 7168)  { src = wv; dst = wqkvb + 2097152; bid -= 6144; }
  else if (bid < 8192)  { src = wo; dst = wob;             bid -= 7168; }
  else if (bid < 12288) { src = w1; dst = w1b;             bid -= 8192; }
  else                  { src = w2; dst = w2b;             bid -= 12288; }
  int i = (bid * 256 + threadIdx.x) * 4;
  float4 v = *(const float4*)(src + i);
  uint2 ov;
  ov.x = (unsigned)f2b(v.x) | ((unsigned)f2b(v.y) << 16);
  ov.y = (unsigned)f2b(v.z) | ((unsigned)f2b(v.w) << 16);
  *(uint2*)(dst + i) = ov;
}

// ---------------- RoPE cos/sin table: [2048 s][32 j] ----------------
__global__ __launch_bounds__(256) void rope_tab_kernel(float2* __restrict__ tab) {
  int idx = blockIdx.x * 256 + threadIdx.x;
  int s = idx >> 5, j = idx & 31;
  float inv = exp2f(-(float)j * (13.287712379549449f / 32.0f));
  float sn, cs;
  sincosf((float)s * inv, &sn, &cs);
  tab[idx] = make_float2(cs, sn);
}

// ---------------- GEMM: C[M,N] = A[M,K] * B[N,K]^T, bf16, f32 acc ----------------
template<int EPI, int BM>
__global__ __launch_bounds__(256) void gemm_bt(
    const u16* __restrict__ A, const u16* __restrict__ B,
    u16* __restrict__ C, const float* __restrict__ bias,
    int M, int N, int K)
{
  constexpr int MT = BM / 32;
  __shared__ __align__(16) u16 As[BM * 64];
  __shared__ __align__(16) u16 Bs[128 * 64];
  const int tid = threadIdx.x;
  const int lane = tid & 63, wave = tid >> 6;
  const int lr = lane & 15, lg = lane >> 4;
  const int wm = wave >> 1, wn = wave & 1;

  const int nwg = gridDim.x * gridDim.y;
  const int id = blockIdx.y * gridDim.x + blockIdx.x;
  const int nid = (id & 7) * (nwg >> 3) + (id >> 3);
  const int bx = nid % gridDim.x, by = nid / gridDim.x;

  const int srow = tid >> 3;
  const int scsw = ((tid & 7) * 8) ^ ((srow & 7) << 3);
  const size_t abase = (size_t)(by * BM + srow) * K + scsw;
  const size_t bbase = (size_t)(bx * 128 + srow) * K + scsw;

  int aoff[MT][2], boff[4][2];
  #pragma unroll
  for (int mt = 0; mt < MT; mt++) {
    int row = wm * (BM / 2) + mt * 16 + lr;
    #pragma unroll
    for (int kk = 0; kk < 2; kk++)
      aoff[mt][kk] = row * 64 + ((kk * 32 + lg * 8) ^ ((row & 7) << 3));
  }
  #pragma unroll
  for (int nt = 0; nt < 4; nt++) {
    int row = wn * 64 + nt * 16 + lr;
    #pragma unroll
    for (int kk = 0; kk < 2; kk++)
      boff[nt][kk] = row * 64 + ((kk * 32 + lg * 8) ^ ((row & 7) << 3));
  }

  f32x4 acc[MT][4];
  #pragma unroll
  for (int i = 0; i < MT; i++)
    #pragma unroll
    for (int j = 0; j < 4; j++) acc[i][j] = (f32x4){0.f, 0.f, 0.f, 0.f};

  for (int k0 = 0; k0 < K; k0 += 64) {
    __syncthreads();
    #pragma unroll
    for (int h = 0; h < MT; h++)
      gload16(A + abase + (size_t)(h * 32) * K + k0, &As[h * 2048 + tid * 8]);
    #pragma unroll
    for (int h = 0; h < 4; h++)
      gload16(B + bbase + (size_t)(h * 32) * K + k0, &Bs[h * 2048 + tid * 8]);
    __syncthreads();
    #pragma unroll
    for (int kk = 0; kk < 2; kk++) {
      bf16x8 af[MT], bfr[4];
      #pragma unroll
      for (int mt = 0; mt < MT; mt++) af[mt] = *(const bf16x8*)&As[aoff[mt][kk]];
      #pragma unroll
      for (int nt = 0; nt < 4; nt++) bfr[nt] = *(const bf16x8*)&Bs[boff[nt][kk]];
      #pragma unroll
      for (int mt = 0; mt < MT; mt++)
        #pragma unroll
        for (int nt = 0; nt < 4; nt++)
          acc[mt][nt] = __builtin_amdgcn_mfma_f32_16x16x32_bf16(af[mt], bfr[nt], acc[mt][nt], 0, 0, 0);
    }
  }

  #pragma unroll
  for (int mt = 0; mt < MT; mt++)
    #pragma unroll
    for (int nt = 0; nt < 4; nt++) {
      const int row = by * BM + wm * (BM / 2) + mt * 16 + lg * 4;
      const int col = bx * 128 + wn * 64 + nt * 16 + lr;
      const float bv = (EPI >= 1) ? bias[col] : 0.f;
      #pragma unroll
      for (int r = 0; r < 4; r++) {
        float x = acc[mt][nt][r] + bv;
        if (EPI == 2) x = 0.5f * x * (1.f + erff(x * 0.70710678118654752f));
        C[(size_t)(row + r) * N + col] = f2b(x);
      }
    }
}

// ---------------- RoPE + reshape [M,stride] -> [B,H,S,64] ----------------
__global__ __launch_bounds__(256) void rope_kernel(
    const u16* __restrict__ qp, const u16* __restrict__ kp, int stride,
    const float2* __restrict__ tab, u16* __restrict__ qr, u16* __restrict__ kr)
{
  const int gid = blockIdx.x * 4 + (threadIdx.x >> 6);
  const int lane = threadIdx.x & 63;
  const int s = gid & 2047;
  const int bh = gid >> 11;
  const int h = bh & 15, b = bh >> 4;
  const int j = lane & 31;
  float2 t = tab[s * 32 + j];
  const float cs = t.x, sn = t.y;
  const size_t base = (size_t)(b * 2048 + s) * stride + h * 64;
  unsigned int qv = *(const unsigned int*)(qp + base + 2 * j);
  unsigned int kv = *(const unsigned int*)(kp + base + 2 * j);
  float q1 = b2f((u16)qv), q2 = b2f((u16)(qv >> 16));
  float k1 = b2f((u16)kv), k2 = b2f((u16)(kv >> 16));
  float qo = (lane < 32) ? (q1 * cs - q2 * sn) : (q1 * sn + q2 * cs);
  float ko = (lane < 32) ? (k1 * cs - k2 * sn) : (k1 * sn + k2 * cs);
  qr[(size_t)gid * 64 + lane] = f2b(qo);
  kr[(size_t)gid * 64 + lane] = f2b(ko);
}

// ---------------- V transpose: [M,stride] -> [B,H,64,S] ----------------
__global__ __launch_bounds__(256) void vtrans_kernel(
    const u16* __restrict__ vp, int stride, u16* __restrict__ vT)
{
  __shared__ u16 t[64][65];
  const int sc = blockIdx.x & 31;
  const int bh = blockIdx.x >> 5;
  const int h = bh & 15, b = bh >> 4;
  const int tid = threadIdx.x;
  #pragma unroll
  for (int i = 0; i < 16; i++) {
    int idx = i * 256 + tid;
    int sl = idx >> 6, d = idx & 63;
    t[sl][d] = vp[(size_t)(b * 2048 + sc * 64 + sl) * stride + h * 64 + d];
  }
  __syncthreads();
  #pragma unroll
  for (int i = 0; i < 16; i++) {
    int idx = i * 256 + tid;
    int d = idx >> 6, sl = idx & 63;
    vT[((size_t)bh * 64 + d) * 2048 + sc * 64 + sl] = t[sl][d];
  }
}

// ---------------- Flash attention: swapped-operand, P-in-register ----------------
// QK^T as mfma(K,Q) -> lane owns one q-row (q=lr), k rows in regs.
// P redistributed to PV B-fragment layout via cvt_pk + ds_bpermute.
__global__ __launch_bounds__(256) void attn_kernel(
    const u16* __restrict__ qr, const u16* __restrict__ kr,
    const u16* __restrict__ vT, const float* __restrict__ rel_tab,
    u16* __restrict__ o)
{
  __shared__ __align__(16) u16 Ks[2][64 * 64];
  __shared__ __align__(16) u16 Vs[2][64 * 64];
  __shared__ float bias_s[64];

  const int tid = threadIdx.x;
  const int lane = tid & 63, wave = tid >> 6;
  const int lr = lane & 15, lg = lane >> 4;

  const int id = blockIdx.x;
  const int nid = (id & 7) * 128 + (id >> 3);
  const int bh = nid >> 5, qc = nid & 31;
  const int h = bh & 15, b = bh >> 4;
  const int q0 = qc * 64 + wave * 16;

  if (tid < 63) bias_s[tid] = rel_tab[tid * 16 + h] * 1.4426950408889634f;

  const u16* qb = qr + (size_t)bh * 2048 * 64;
  const u16* kb = kr + (size_t)bh * 2048 * 64;
  const u16* vb = vT + (size_t)bh * 64 * 2048;

  // Q as B-operand: lane holds Q[q0+lr][ks*32 + lg*8 .. +8)
  bf16x8 qf[2];
  qf[0] = *(const bf16x8*)(qb + (size_t)(q0 + lr) * 64 + lg * 8);
  qf[1] = *(const bf16x8*)(qb + (size_t)(q0 + lr) * 64 + 32 + lg * 8);

  const int srow = tid >> 3;
  const int scsw = ((tid & 7) * 8) ^ ((srow & 7) << 3);

  // A-operand frag offsets (rows nt*16+lr), both-sides swizzle
  int koff[4][2];
  #pragma unroll
  for (int nt = 0; nt < 4; nt++)
    #pragma unroll
    for (int ks = 0; ks < 2; ks++)
      koff[nt][ks] = (nt * 16 + lr) * 64 + ((ks * 32 + lg * 8) ^ ((lr & 7) << 3));

  // prefetch chunk 0
  #pragma unroll
  for (int hh = 0; hh < 2; hh++) {
    gload16(kb + (size_t)(hh * 32 + srow) * 64 + scsw, &Ks[0][hh * 2048 + tid * 8]);
    gload16(vb + (size_t)(hh * 32 + srow) * 2048 + scsw, &Vs[0][hh * 2048 + tid * 8]);
  }

  float mrow = -1e30f, lpart = 0.f;
  f32x4 oacc[4];
  #pragma unroll
  for (int nt = 0; nt < 4; nt++) oacc[nt] = (f32x4){0.f, 0.f, 0.f, 0.f};

  const float SC = 0.18033688011112042f;  // 0.125 * log2(e)
  // bpermute source lanes: word w from lane (lr, (lg&1)*2 + (w>>1))
  const int idx_lo = 4 * (lr + 16 * ((lg & 1) * 2));
  const int idx_hi = idx_lo + 64;
  const bool hiSel = (lg >= 2);

  int cur = 0;
  for (int kc = 0; kc < 32; kc++) {
    const int k0 = kc * 64;
    __syncthreads();  // drains vmcnt -> buf[cur] ready; prior reads of buf[cur^1] done
    if (kc < 31) {
      const int kn = k0 + 64;
      #pragma unroll
      for (int hh = 0; hh < 2; hh++) {
        gload16(kb + (size_t)(kn + hh * 32 + srow) * 64 + scsw, &Ks[cur ^ 1][hh * 2048 + tid * 8]);
        gload16(vb + (size_t)(hh * 32 + srow) * 2048 + kn + scsw, &Vs[cur ^ 1][hh * 2048 + tid * 8]);
      }
    }
    const u16* Kc = Ks[cur];
    const u16* Vc = Vs[cur];

    // S^T = K * Q^T : sacc[nt][r] = S[q=lr][k = k0 + nt*16 + lg*4 + r]
    f32x4 sacc[4];
    #pragma unroll
    for (int nt = 0; nt < 4; nt++) sacc[nt] = (f32x4){0.f, 0.f, 0.f, 0.f};
    __builtin_amdgcn_s_setprio(1);
    #pragma unroll
    for (int ks = 0; ks < 2; ks++)
      #pragma unroll
      for (int nt = 0; nt < 4; nt++) {
        bf16x8 kf = *(const bf16x8*)&Kc[koff[nt][ks]];
        sacc[nt] = __builtin_amdgcn_mfma_f32_16x16x32_bf16(kf, qf[ks], sacc[nt], 0, 0, 0);
      }
    __builtin_amdgcn_s_setprio(0);

    // scale (log2 domain) + rel bias; wave-uniform fast path off-diagonal
    float p[4][4];
    const int dmin = q0 - k0 - 63, dmax = q0 + 15 - k0;
    if (dmin >= 31 || dmax <= -31) {
      const float c = bias_s[dmin >= 31 ? 62 : 0];
      #pragma unroll
      for (int nt = 0; nt < 4; nt++)
        #pragma unroll
        for (int r = 0; r < 4; r++) p[nt][r] = sacc[nt][r] * SC + c;
    } else {
      #pragma unroll
      for (int nt = 0; nt < 4; nt++)
        #pragma unroll
        for (int r = 0; r < 4; r++) {
          int d = (q0 + lr) - (k0 + nt * 16 + lg * 4 + r);
          d = d < -31 ? -31 : (d > 31 ? 31 : d);
          p[nt][r] = sacc[nt][r] * SC + bias_s[d + 31];
        }
    }

    // row max: 16 local + 2 cross-lg shuffles
    float rm = p[0][0];
    #pragma unroll
    for (int nt = 0; nt < 4; nt++)
      #pragma unroll
      for (int r = 0; r < 4; r++) rm = fmaxf(rm, p[nt][r]);
    rm = fmaxf(rm, __shfl_xor(rm, 16));
    rm = fmaxf(rm, __shfl_xor(rm, 32));

    // defer-max (T13): 8 nats = 11.5 in log2
    if (!__all(rm <= mrow + 11.5f)) {
      float mnew = fmaxf(mrow, rm);
      float sc = exp2f(mrow - mnew);
      lpart *= sc;
      #pragma unroll
      for (int nt = 0; nt < 4; nt++) oacc[nt] *= sc;
      mrow = mnew;
    }

    // exp2 + pack to bf16 pairs (k-minor): pk[nt][i] = (p[nt][2i], p[nt][2i+1])
    unsigned int pk[4][2];
    #pragma unroll
    for (int nt = 0; nt < 4; nt++)
      #pragma unroll
      for (int i = 0; i < 2; i++) {
        float pa = exp2f(p[nt][2 * i] - mrow);
        float pb = exp2f(p[nt][2 * i + 1] - mrow);
        lpart += pa + pb;
        unsigned int pr;
        asm("v_cvt_pk_bf16_f32 %0, %1, %2" : "=v"(pr) : "v"(pa), "v"(pb));
        pk[nt][i] = pr;
      }

    // exchange to PV B-fragment layout + PV mfma
    __builtin_amdgcn_s_setprio(1);
    #pragma unroll
    for (int ks = 0; ks < 2; ks++) {
      int w0a = __builtin_amdgcn_ds_bpermute(idx_lo, (int)pk[ks * 2][0]);
      int w0b = __builtin_amdgcn_ds_bpermute(idx_lo, (int)pk[ks * 2 + 1][0]);
      int w1a = __builtin_amdgcn_ds_bpermute(idx_lo, (int)pk[ks * 2][1]);
      int w1b = __builtin_amdgcn_ds_bpermute(idx_lo, (int)pk[ks * 2 + 1][1]);
      int w2a = __builtin_amdgcn_ds_bpermute(idx_hi, (int)pk[ks * 2][0]);
      int w2b = __builtin_amdgcn_ds_bpermute(idx_hi, (int)pk[ks * 2 + 1][0]);
      int w3a = __builtin_amdgcn_ds_bpermute(idx_hi, (int)pk[ks * 2][1]);
      int w3b = __builtin_amdgcn_ds_bpermute(idx_hi, (int)pk[ks * 2 + 1][1]);
      int4 bw;
      bw.x = hiSel ? w0b : w0a;
      bw.y = hiSel ? w1b : w1a;
      bw.z = hiSel ? w2b : w2a;
      bw.w = hiSel ? w3b : w3a;
      bf16x8 pf = *(bf16x8*)&bw;
      #pragma unroll
      for (int nt = 0; nt < 4; nt++) {
        bf16x8 vf = *(const bf16x8*)&Vc[koff[nt][ks]];
        oacc[nt] = __builtin_amdgcn_mfma_f32_16x16x32_bf16(vf, pf, oacc[nt], 0, 0, 0);
      }
    }
    __builtin_amdgcn_s_setprio(0);
    cur ^= 1;
  }

  lpart += __shfl_xor(lpart, 16);
  lpart += __shfl_xor(lpart, 32);
  const float inv = 1.0f / lpart;
  const size_t obase = (size_t)(b * 2048 + q0 + lr) * 1024 + h * 64;
  #pragma unroll
  for (int nt = 0; nt < 4; nt++) {
    uint2 st;
    st.x = (unsigned)f2b(oacc[nt][0] * inv) | ((unsigned)f2b(oacc[nt][1] * inv) << 16);
    st.y = (unsigned)f2b(oacc[nt][2] * inv) | ((unsigned)f2b(oacc[nt][3] * inv) << 16);
    *(uint2*)(o + obase + nt * 16 + lg * 4) = st;
  }
}

// ---------------- LayerNorm 1: h = LN(x + ao), bf16 out ----------------
__global__ __launch_bounds__(256) void ln1_kernel(
    const float* __restrict__ x, const u16* __restrict__ ao,
    const float* __restrict__ g, const float* __restrict__ bta,
    u16* __restrict__ hb)
{
  const int row = blockIdx.x, tid = threadIdx.x;
  const int wave = tid >> 6, lane = tid & 63;
  float v[4]; float s = 0.f, s2 = 0.f;
  #pragma unroll
  for (int j = 0; j < 4; j++) {
    int c = tid + j * 256;
    float t = x[(size_t)row * 1024 + c] + b2f(ao[(size_t)row * 1024 + c]);
    v[j] = t; s += t; s2 += t * t;
  }
  #pragma unroll
  for (int off = 32; off >= 1; off >>= 1) { s += __shfl_down(s, off); s2 += __shfl_down(s2, off); }
  __shared__ float rs[4], rs2[4];
  if (lane == 0) { rs[wave] = s; rs2[wave] = s2; }
  __syncthreads();
  s = rs[0] + rs[1] + rs[2] + rs[3];
  s2 = rs2[0] + rs2[1] + rs2[2] + rs2[3];
  float mean = s * (1.f / 1024.f);
  float var = s2 * (1.f / 1024.f) - mean * mean;
  float inv = rsqrtf(var + 1e-5f);
  #pragma unroll
  for (int j = 0; j < 4; j++) {
    int c = tid + j * 256;
    hb[(size_t)row * 1024 + c] = f2b((v[j] - mean) * inv * g[c] + bta[c]);
  }
}

// ---------------- LayerNorm 2: out = LN(hb + fb), f32 out ----------------
__global__ __launch_bounds__(256) void ln2_kernel(
    const u16* __restrict__ hb, const u16* __restrict__ fb,
    const float* __restrict__ g, const float* __restrict__ bta,
    float* __restrict__ out)
{
  const int row = blockIdx.x, tid = threadIdx.x;
  const int wave = tid >> 6, lane = tid & 63;
  float v[4]; float s = 0.f, s2 = 0.f;
  #pragma unroll
  for (int j = 0; j < 4; j++) {
    int c = tid + j * 256;
    float t = b2f(hb[(size_t)row * 1024 + c]) + b2f(fb[(size_t)row * 1024 + c]);
    v[j] = t; s += t; s2 += t * t;
  }
  #pragma unroll
  for (int off = 32; off >= 1; off >>= 1) { s += __shfl_down(s, off); s2 += __shfl_down(s2, off); }
  __shared__ float rs[4], rs2[4];
  if (lane == 0) { rs[wave] = s; rs2[wave] = s2; }
  __syncthreads();
  s = rs[0] + rs[1] + rs[2] + rs[3];
  s2 = rs2[0] + rs2[1] + rs2[2] + rs2[3];
  float mean = s * (1.f / 1024.f);
  float var = s2 * (1.f / 1024.f) - mean * mean;
  float inv = rsqrtf(var + 1e-5f);
  #pragma unroll
  for (int j = 0; j < 4; j++) {
    int c = tid + j * 256;
    out[(size_t)row * 1024 + c] = (v[j] - mean) * inv * g[c] + bta[c];
  }
}

// ---------------- host launcher ----------------
extern "C" void kernel_launch(void* const* d_in, const int* in_sizes, int n_in,
                              void* d_out, int out_size, void* d_ws, size_t ws_size,
                              hipStream_t stream)
{
  const float* x    = (const float*)d_in[0];
  const float* wq   = (const float*)d_in[1];
  const float* wk   = (const float*)d_in[2];
  const float* wv   = (const float*)d_in[3];
  const float* wo   = (const float*)d_in[4];
  const float* wo_b = (const float*)d_in[5];
  const float* rel  = (const float*)d_in[6];
  const float* ln1g = (const float*)d_in[7];
  const float* ln1b = (const float*)d_in[8];
  const float* ln2g = (const float*)d_in[9];
  const float* ln2b = (const float*)d_in[10];
  const float* w1   = (const float*)d_in[11];
  const float* b1   = (const float*)d_in[12];
  const float* w2   = (const float*)d_in[13];
  const float* b2   = (const float*)d_in[14];
  float* out = (float*)d_out;
  char* w = (char*)d_ws;

  if (ws_size < (size_t)90 * MB) return;

  u16* xb    = (u16*)(w + 0 * MB);
  u16* wqkvb = (u16*)(w + 8 * MB);
  u16* wob   = (u16*)(w + 14 * MB);
  u16* w1b   = (u16*)(w + 16 * MB);
  u16* w2b   = (u16*)(w + 24 * MB);
  u16* qkv   = (u16*)(w + 32 * MB);
  u16* ob    = (u16*)(w + 32 * MB);
  u16* ao    = (u16*)(w + 40 * MB);
  u16* hb    = (u16*)(w + 48 * MB);
  u16* qrb   = (u16*)(w + 56 * MB);
  u16* krb   = (u16*)(w + 64 * MB);
  u16* vTb   = (u16*)(w + 72 * MB);
  u16* gb    = (u16*)(w + 56 * MB);
  u16* fb    = (u16*)(w + 0 * MB);
  float2* tab = (float2*)(w + 88 * MB);   // 512 KB cos/sin table

  const int M = 4096, D = 1024, F = 4096;

  rope_tab_kernel<<<dim3(256), 256, 0, stream>>>(tab);
  f2b_all<<<dim3(16384), 256, 0, stream>>>(x, wq, wk, wv, wo, w1, w2,
                                           xb, wqkvb, wob, w1b, w2b);

  gemm_bt<0, 128><<<dim3(3 * D / 128, M / 128), 256, 0, stream>>>(xb, wqkvb, qkv, nullptr, M, 3 * D, D);

  rope_kernel<<<dim3(16384), 256, 0, stream>>>(qkv, qkv + 1024, 3 * D, tab, qrb, krb);
  vtrans_kernel<<<dim3(1024), 256, 0, stream>>>(qkv + 2048, 3 * D, vTb);

  attn_kernel<<<dim3(1024), 256, 0, stream>>>(qrb, krb, vTb, rel, ob);

  gemm_bt<1, 64><<<dim3(D / 128, M / 64), 256, 0, stream>>>(ob, wob, ao, wo_b, M, D, D);

  ln1_kernel<<<dim3(M), 256, 0, stream>>>(x, ao, ln1g, ln1b, hb);

  gemm_bt<2, 128><<<dim3(F / 128, M / 128), 256, 0, stream>>>(hb, w1b, gb, b1, M, F, D);

  gemm_bt<1, 64><<<dim3(D / 128, M / 64), 256, 0, stream>>>(gb, w2b, fb, b2, M, D, F);

  ln2_kernel<<<dim3(M), 256, 0, stream>>>(hb, fb, ln2g, ln2b, out);
}